// Round 16
// baseline (515.499 us; speedup 1.0000x reference)
//
#include <hip/hip_runtime.h>
#include <hip/hip_bf16.h>

constexpr int SEQ = 2048;
constexpr int EMB = 4096;
constexpr int NH  = 32;
constexpr int HD  = 128;
constexpr int HALF = 64;

typedef __bf16 bf16x8 __attribute__((ext_vector_type(8)));
typedef float  f32x4  __attribute__((ext_vector_type(4)));
using u16 = unsigned short;
typedef u16 ushort8 __attribute__((ext_vector_type(8)));
typedef u16 u16x4 __attribute__((ext_vector_type(4)));

__device__ inline float bf2f(u16 u) {
  union { unsigned int i; float f; } v; v.i = ((unsigned int)u) << 16; return v.f;
}
__device__ inline u16 f2bf(float f) {
  union { __bf16 b; u16 u; } v; v.b = (__bf16)f; return v.u;
}

#define GLL16(gp, lp) __builtin_amdgcn_global_load_lds( \
    (const __attribute__((address_space(1))) void*)(gp), \
    (__attribute__((address_space(3))) void*)(lp), 16, 0, 0)

// ---------------- fp32 -> bf16 conversion (vectorized) ----------------
__global__ void k_f32_to_bf16(const float* __restrict__ in, u16* __restrict__ out, int n) {
  int i = (blockIdx.x * blockDim.x + threadIdx.x) * 8;
  if (i >= n) return;
  f32x4 a = *(const f32x4*)(in + i);
  f32x4 b = *(const f32x4*)(in + i + 4);
  ushort8 o;
  o[0] = f2bf(a[0]); o[1] = f2bf(a[1]); o[2] = f2bf(a[2]); o[3] = f2bf(a[3]);
  o[4] = f2bf(b[0]); o[5] = f2bf(b[1]); o[6] = f2bf(b[2]); o[7] = f2bf(b[3]);
  *(ushort8*)(out + i) = o;
}

// 3 weight matrices (each EMB*EMB = 2^24 elems) -> contiguous bf16 buffer
__global__ void k_w3_to_bf16(const float* __restrict__ w0, const float* __restrict__ w1,
                             const float* __restrict__ w2, u16* __restrict__ out) {
  size_t i = ((size_t)blockIdx.x * blockDim.x + threadIdx.x) * 8;
  int seg = (int)(i >> 24);
  size_t off = i & ((1u << 24) - 1);
  const float* src = (seg == 0) ? w0 : (seg == 1) ? w1 : w2;
  f32x4 a = *(const f32x4*)(src + off);
  f32x4 b = *(const f32x4*)(src + off + 4);
  ushort8 o;
  o[0] = f2bf(a[0]); o[1] = f2bf(a[1]); o[2] = f2bf(a[2]); o[3] = f2bf(a[3]);
  o[4] = f2bf(b[0]); o[5] = f2bf(b[1]); o[6] = f2bf(b[2]); o[7] = f2bf(b[3]);
  *(ushort8*)(out + i) = o;
}

// ---------------- RoPE cos/sin table (fp64 for exactness) ----------------
__global__ void k_rope_table(const int* __restrict__ pos, float* __restrict__ tab) {
  int idx = blockIdx.x * blockDim.x + threadIdx.x;
  if (idx >= SEQ * HALF) return;
  int s = idx >> 6, d = idx & 63;
  double invf = pow(10000.0, -(double)d / 64.0);
  double ang = (double)pos[s] * invf;
  tab[idx * 2]     = (float)cos(ang);
  tab[idx * 2 + 1] = (float)sin(ang);
}

// ---------------- RoPE apply (in-place on bf16, optional 1/sqrt(D) fold) ----------------
__global__ void k_rope(u16* __restrict__ X, const float* __restrict__ tab, float scale) {
  int idx = blockIdx.x * blockDim.x + threadIdx.x;   // SEQ*NH*HALF
  if (idx >= SEQ * NH * HALF) return;
  int d = idx & 63;
  int h = (idx >> 6) & 31;
  int s = idx >> 11;
  u16* p = X + (size_t)s * EMB + h * HD + d;
  float x1 = bf2f(p[0]), x2 = bf2f(p[HALF]);
  float c  = tab[(s * HALF + d) * 2];
  float sn = tab[(s * HALF + d) * 2 + 1];
  p[0]    = f2bf((x1 * c - x2 * sn) * scale);
  p[HALF] = f2bf((x2 * c + x1 * sn) * scale);
}

// ======== GEMM: TBMxTBN tile, BK=32, 4 LDS buffers, 3-ahead, PHASE-SPLIT ========
// r14 outer ledger (race-proven) + NEW intra-tile barrier pairs bracketing each
// MFMA cluster (T3/T5: barrier-aligned clusters create wave role-split so
// setprio arbitrates MFMA-entering vs load-issuing waves).
// Per tile: { counted vmcnt; s_barrier; [reads A1/B + stageA(t+3)]; s_barrier;
//   setprio MFMA x(MA/2*NB); s_barrier; [reads A2 + stageB(t+3)]; s_barrier;
//   setprio MFMA }. s_barrier = rendezvous only (no drain); compiler inserts
// fine lgkmcnt for read->MFMA deps. Stage(t+3) targets buf[(t-1)&3], whose
// reads retired in tile t-1 — unchanged from r8/r14.
// mode: 0 bf16 [M][N], 1 f32 [M][N], 2 bf16 V^T [n][M], 3 QKV fused.
template<int TBM, int TBN>
__global__ __launch_bounds__(512, 1) void k_qkv4(
    const u16* __restrict__ Ag, const u16* __restrict__ Wg,
    const float* __restrict__ b0, const float* __restrict__ b1, const float* __restrict__ b2,
    void* __restrict__ C0, void* __restrict__ C1, void* __restrict__ C2,
    int M, int N, int K, int mode)
{
  constexpr int LDA = TBM / 128;            // stageA loads per thread (2 or 1)
  constexpr int MA  = TBM / 32;             // A frags per wave (8 or 4)
  constexpr int NB  = TBN / 64;             // B frags per wave (4 or 3)
  constexpr int WNC = TBN / 4;              // cols per wave (64 or 48)
  __shared__ alignas(16) u16 As[4][TBM * 32];
  __shared__ alignas(16) u16 Bs[4][TBN * 32];

  int tid = threadIdx.x;
  int lane = tid & 63, wid = tid >> 6;
  int wm = wid >> 2, wn = wid & 3;          // 2 x 4 waves
  int l15 = lane & 15, lhi = lane >> 4;

  int NBY = M / TBM, NBX = N / TBN;
  int wg = blockIdx.x;
  int xcd = wg & 7, sgl = wg >> 3;
  int by = sgl % NBY, bxl = sgl / NBY;
  int bx = xcd * (NBX >> 3) + bxl;
  int m0 = by * TBM, n0 = bx * TBN;

  auto stageA = [&](int b, int k0) {
#pragma unroll
    for (int ld = 0; ld < LDA; ld++) {
      int idx = ld * 512 + tid;
      int row = idx >> 2, pb = idx & 3;
      int kb = (pb - row - (row >> 2)) & 3;
      GLL16(Ag + (size_t)(m0 + row) * K + k0 + kb * 8, &As[b][idx * 8]);
    }
  };
  auto stageB = [&](int b, int k0) {
    {
      int idx = tid;
      int row = idx >> 2, pb = idx & 3;
      int kb = (pb - row - (row >> 2)) & 3;
      GLL16(Wg + (size_t)(n0 + row) * K + k0 + kb * 8, &Bs[b][idx * 8]);
    }
    if constexpr (TBN == 256) {
      int idx = 512 + tid;
      int row = idx >> 2, pb = idx & 3;
      int kb = (pb - row - (row >> 2)) & 3;
      GLL16(Wg + (size_t)(n0 + row) * K + k0 + kb * 8, &Bs[b][idx * 8]);
    } else {
      if (wid < 4) {
        int idx = 512 + tid;
        int row = idx >> 2, pb = idx & 3;
        int kb = (pb - row - (row >> 2)) & 3;
        GLL16(Wg + (size_t)(n0 + row) * K + k0 + kb * 8, &Bs[b][idx * 8]);
      }
    }
  };

  f32x4 acc[MA][NB] = {};
  int KT = K >> 5;

  stageA(0, 0);  stageB(0, 0);
  stageA(1, 32); stageB(1, 32);
  stageA(2, 64); stageB(2, 64);

  for (int t = 0; t < KT; t++) {
    if constexpr (TBN == 256) {
      if (t < KT - 2)       asm volatile("s_waitcnt vmcnt(%0)" :: "n"(2 * (LDA + 2)) : "memory");
      else if (t == KT - 2) asm volatile("s_waitcnt vmcnt(%0)" :: "n"(LDA + 2) : "memory");
      else                  asm volatile("s_waitcnt vmcnt(0)" ::: "memory");
    } else {
      if (t < KT - 2) {
        if (wid < 4) asm volatile("s_waitcnt vmcnt(%0)" :: "n"(2 * (LDA + 2)) : "memory");
        else         asm volatile("s_waitcnt vmcnt(%0)" :: "n"(2 * (LDA + 1)) : "memory");
      } else if (t == KT - 2) {
        if (wid < 4) asm volatile("s_waitcnt vmcnt(%0)" :: "n"(LDA + 2) : "memory");
        else         asm volatile("s_waitcnt vmcnt(%0)" :: "n"(LDA + 1) : "memory");
      } else {
        asm volatile("s_waitcnt vmcnt(0)" ::: "memory");
      }
    }
    __builtin_amdgcn_s_barrier();
    __builtin_amdgcn_sched_barrier(0);

    const u16* as = &As[t & 3][0];
    const u16* bs = &Bs[t & 3][0];
    bool st = (t + 3) < KT;
    int sb = (t + 3) & 3, sk = (t + 3) << 5;

    // ---- phase 1: reads (B-frags + first A-half) || stageA(t+3) ----
    bf16x8 bfr[NB], afA[MA / 2];
#pragma unroll
    for (int q = 0; q < NB; q++) {
      int row = wn * WNC + q * 16 + l15;
      bfr[q] = *(const bf16x8*)&bs[row * 32 + ((lhi + row + (row >> 2)) & 3) * 8];
    }
#pragma unroll
    for (int p = 0; p < MA / 2; p++) {
      int row = wm * (TBM / 2) + p * 16 + l15;
      afA[p] = *(const bf16x8*)&as[row * 32 + ((lhi + row + (row >> 2)) & 3) * 8];
    }
    if (st) stageA(sb, sk);
    __builtin_amdgcn_s_barrier();          // align waves -> MFMA cluster role-split
    __builtin_amdgcn_sched_barrier(0);
    __builtin_amdgcn_s_setprio(1);
#pragma unroll
    for (int p = 0; p < MA / 2; p++)
#pragma unroll
      for (int q = 0; q < NB; q++)
        acc[p][q] = __builtin_amdgcn_mfma_f32_16x16x32_bf16(afA[p], bfr[q], acc[p][q], 0, 0, 0);
    __builtin_amdgcn_s_setprio(0);
    __builtin_amdgcn_s_barrier();
    __builtin_amdgcn_sched_barrier(0);

    // ---- phase 2: reads (second A-half) || stageB(t+3) ----
    bf16x8 afB[MA / 2];
#pragma unroll
    for (int p = 0; p < MA / 2; p++) {
      int row = wm * (TBM / 2) + (MA / 2) * 16 + p * 16 + l15;
      afB[p] = *(const bf16x8*)&as[row * 32 + ((lhi + row + (row >> 2)) & 3) * 8];
    }
    if (st) stageB(sb, sk);
    __builtin_amdgcn_s_barrier();
    __builtin_amdgcn_sched_barrier(0);
    __builtin_amdgcn_s_setprio(1);
#pragma unroll
    for (int p = 0; p < MA / 2; p++)
#pragma unroll
      for (int q = 0; q < NB; q++)
        acc[MA / 2 + p][q] = __builtin_amdgcn_mfma_f32_16x16x32_bf16(afB[p], bfr[q], acc[MA / 2 + p][q], 0, 0, 0);
    __builtin_amdgcn_s_setprio(0);
  }

#pragma unroll
  for (int p = 0; p < MA; p++) {
    int m = m0 + wm * (TBM / 2) + p * 16 + lhi * 4;
#pragma unroll
    for (int q = 0; q < NB; q++) {
      int n = n0 + wn * WNC + q * 16 + l15;
      const float* bias; void* Cout; int mode_l, nl;
      if (mode == 3) {
        int seg = n >> 12; nl = n & 4095;
        bias = (seg == 0) ? b0 : (seg == 1) ? b1 : b2;
        Cout = (seg == 0) ? C0 : (seg == 1) ? C1 : C2;
        mode_l = (seg == 2) ? 2 : 0;
      } else { bias = b0; Cout = C0; mode_l = mode; nl = n; }
      float bs2 = bias[nl];
      if (mode_l == 2) {
        u16x4 pk;
#pragma unroll
        for (int r = 0; r < 4; r++) pk[r] = f2bf(acc[p][q][r] + bs2);
        *(u16x4*)&((u16*)Cout)[(size_t)nl * M + m] = pk;   // V^T
      } else if (mode_l == 1) {
#pragma unroll
        for (int r = 0; r < 4; r++)
          ((float*)Cout)[(size_t)(m + r) * EMB + nl] = acc[p][q][r] + bs2;
      } else {
#pragma unroll
        for (int r = 0; r < 4; r++)
          ((u16*)Cout)[(size_t)(m + r) * EMB + nl] = f2bf(acc[p][q][r] + bs2);
      }
    }
  }
}

// ---------------- Flash attention (causal), QB=128, KVB=64, 4-buf pipeline ----------------
constexpr int QB = 128, KVB = 64;

__global__ __launch_bounds__(512) void k_flash(
    const u16* __restrict__ Q, const u16* __restrict__ K, const u16* __restrict__ VT,
    u16* __restrict__ ctx)
{
  __shared__ alignas(16) u16 Ks[4][KVB * 128];   // 4 x 16 KB
  __shared__ alignas(16) u16 Vt[4][HD * 64];     // 4 x 16 KB
  __shared__ alignas(16) u16 Pl[8][16 * 64];     // 16 KB (144 KB total)

  int tid = threadIdx.x, lane = tid & 63, wid = tid >> 6;   // wid 0..7
  int l15 = lane & 15, lhi = lane >> 4;
  int h = blockIdx.y;

  auto stage = [&](int buf, int t2) {
    int kv = t2 * KVB;
#pragma unroll
    for (int it = 0; it < 2; it++) {
      int chunk = tid + it * 512;
      int r = chunk >> 4, bp = chunk & 15;
      GLL16(K + (size_t)(kv + r) * EMB + h * HD + (((bp - r) & 15) << 3), &Ks[buf][chunk * 8]);
    }
#pragma unroll
    for (int it = 0; it < 2; it++) {
      int chunk = tid + it * 512;
      int d = chunk >> 3, bp = chunk & 7;
      GLL16(VT + (size_t)(h * HD + d) * SEQ + kv + (((bp - d) & 7) << 3), &Vt[buf][chunk * 8]);
    }
  };

  for (int pi = 0; pi < 2; pi++) {
    int qb = pi ? (int)blockIdx.x : 15 - (int)blockIdx.x;   // heavy first
    int q0 = qb * QB;
    int qw = q0 + wid * 16;

    bf16x8 qf[4];
#pragma unroll
    for (int kc = 0; kc < 4; kc++)
      qf[kc] = *(const bf16x8*)&Q[(size_t)(qw + l15) * EMB + h * HD + kc * 32 + lhi * 8];

    f32x4 O[8] = {};
    float mrow[4], lrow[4];
#pragma unroll
    for (int r = 0; r < 4; r++) { mrow[r] = -3.0e38f; lrow[r] = 0.f; }

    int nt = 2 * (qb + 1);
    __syncthreads();          // pass boundary: previous pass's LDS reads done
    stage(0, 0);
    if (nt > 1) stage(1, 1);
    if (nt > 2) stage(2, 2);
    for (int t = 0; t < nt; t++) {
      if (t + 2 < nt)       asm volatile("s_waitcnt vmcnt(8)" ::: "memory");
      else if (t + 1 < nt)  asm volatile("s_waitcnt vmcnt(4)" ::: "memory");
      else                  asm volatile("s_waitcnt vmcnt(0)" ::: "memory");
      __builtin_amdgcn_s_barrier();
      __builtin_amdgcn_sched_barrier(0);
      if (t + 3 < nt) stage((t + 3) & 3, t + 3);

      int kv0 = t * KVB;
      if (kv0 > qw + 15) continue;   // fully masked for this wave (sync already uniform)

      const u16* ks = Ks[t & 3];
      const u16* vt = Vt[t & 3];
      float p[4][4];
      bool need_mask = (kv0 + KVB - 1) > qw;
#pragma unroll
      for (int c = 0; c < 4; c++) {
        f32x4 s = {};
        int r0 = c * 16 + l15;
#pragma unroll
        for (int kc = 0; kc < 4; kc++) {
          bf16x8 kf = *(const bf16x8*)&ks[r0 * 128 + (((kc * 4 + lhi) + r0) & 15) * 8];
          s = __builtin_amdgcn_mfma_f32_16x16x32_bf16(qf[kc], kf, s, 0, 0, 0);
        }
#pragma unroll
        for (int r = 0; r < 4; r++) {
          float sv = s[r];
          if (need_mask) {
            int qg = qw + lhi * 4 + r;
            int kg = kv0 + c * 16 + l15;
            if (kg > qg) sv = -3.0e38f;
          }
          p[c][r] = sv;
        }
      }
      float fscale[4];
#pragma unroll
      for (int r = 0; r < 4; r++) {
        float m = fmaxf(fmaxf(p[0][r], p[1][r]), fmaxf(p[2][r], p[3][r]));
#pragma unroll
        for (int x = 1; x < 16; x <<= 1) m = fmaxf(m, __shfl_xor(m, x, 64));
        float mnew = fmaxf(mrow[r], m);
        fscale[r] = __expf(mrow[r] - mnew);
        mrow[r] = mnew;
      }
#pragma unroll
      for (int c = 0; c < 4; c++)
#pragma unroll
        for (int r = 0; r < 4; r++)
          p[c][r] = __expf(p[c][r] - mrow[r]);
#pragma unroll
      for (int r = 0; r < 4; r++) {
        float s = p[0][r] + p[1][r] + p[2][r] + p[3][r];
#pragma unroll
        for (int x = 1; x < 16; x <<= 1) s += __shfl_xor(s, x, 64);
        lrow[r] = lrow[r] * fscale[r] + s;
      }
#pragma unroll
      for (int d = 0; d < 8; d++)
#pragma unroll
        for (int r = 0; r < 4; r++)
          O[d][r] *= fscale[r];
#pragma unroll
      for (int c = 0; c < 4; c++) {
        int kb = c * 2 + (l15 >> 3), klo = l15 & 7;
#pragma unroll
        for (int r = 0; r < 4; r++) {
          int q = lhi * 4 + r;
          Pl[wid][q * 64 + ((kb + (q >> 1)) & 7) * 8 + klo] = f2bf(p[c][r]);
        }
      }
#pragma unroll
      for (int ks2 = 0; ks2 < 2; ks2++) {
        int kb = ks2 * 4 + lhi;
        bf16x8 pf = *(const bf16x8*)&Pl[wid][l15 * 64 + ((kb + (l15 >> 1)) & 7) * 8];
#pragma unroll
        for (int ds = 0; ds < 8; ds++) {
          int d = ds * 16 + l15;
          bf16x8 vf = *(const bf16x8*)&vt[d * 64 + ((kb + d) & 7) * 8];
          O[ds] = __builtin_amdgcn_mfma_f32_16x16x32_bf16(pf, vf, O[ds], 0, 0, 0);
        }
      }
    }

#pragma unroll
    for (int r = 0; r < 4; r++) {
      float inv = 1.f / lrow[r];
      int qg = q0 + wid * 16 + lhi * 4 + r;
#pragma unroll
      for (int ds = 0; ds < 8; ds++)
        ctx[(size_t)qg * EMB + h * HD + ds * 16 + l15] = f2bf(O[ds][r] * inv);
    }
  }
}

// ---------------- launch ----------------
extern "C" void kernel_launch(void* const* d_in, const int* in_sizes, int n_in,
                              void* d_out, int out_size, void* d_ws, size_t ws_size,
                              hipStream_t stream) {
  const float* hs = (const float*)d_in[0];
  const float* wq = (const float*)d_in[1];
  const float* bq = (const float*)d_in[2];
  const float* wk = (const float*)d_in[3];
  const float* bk = (const float*)d_in[4];
  const float* wv = (const float*)d_in[5];
  const float* bv = (const float*)d_in[6];
  const float* wo = (const float*)d_in[7];
  const float* bo = (const float*)d_in[8];
  const int*  pos = (const int*)d_in[9];

  const size_t SE = (size_t)SEQ * EMB;   // 8M elems
  const size_t EE = (size_t)EMB * EMB;   // 16M elems = 2^24
  const float qscale = 1.0f / 11.313708498984761f;  // 1/sqrt(128)

  char* ws = (char*)d_ws;
  size_t off = 0;
  auto alloc = [&](size_t b) { size_t o = off; off += (b + 255) & ~(size_t)255; return o; };

  size_t need_fused = ((SE * 2 + 255) & ~255ULL) + ((EE * 6 + 255) & ~255ULL) +
                      3 * ((SE * 2 + 255) & ~255ULL) + ((size_t)SEQ * HALF * 8 + 255);
  bool fused = ws_size >= need_fused + 4096;

  u16*  hsb = (u16*)(ws + alloc(SE * 2));
  u16*  wb  = (u16*)(ws + alloc(fused ? EE * 6 : EE * 2));  // fused: wq|wk|wv, reused for wo
  u16*  Qb  = (u16*)(ws + alloc(SE * 2));
  u16*  Kb  = (u16*)(ws + alloc(SE * 2));
  u16*  VTb = (u16*)(ws + alloc(SE * 2));                   // V^T, [E][S]
  float* tab = (float*)(ws + alloc((size_t)SEQ * HALF * 2 * 4));
  u16*  ctxb = hsb;   // hs dead after QKV GEMM; flash output reuses it

  dim3 cb(256);
  k_f32_to_bf16<<<dim3(SE / 2048), cb, 0, stream>>>(hs, hsb, (int)SE);
  k_rope_table<<<dim3(SEQ * HALF / 256), cb, 0, stream>>>(pos, tab);

  if (fused) {
    k_w3_to_bf16<<<dim3(3 * EE / 2048), cb, 0, stream>>>(wq, wk, wv, wb);
    // fused QKV GEMM: 256x192 tile -> grid 512 = 2 EXACT rounds of 256 CUs
    k_qkv4<256, 192><<<dim3(512), dim3(512), 0, stream>>>(
        hsb, wb, bq, bk, bv, (void*)Qb, (void*)Kb, (void*)VTb, SEQ, 3 * EMB, EMB, 3);
  } else {
    k_f32_to_bf16<<<dim3(EE / 2048), cb, 0, stream>>>(wq, wb, (int)EE);
    k_qkv4<256, 256><<<dim3(128), dim3(512), 0, stream>>>(
        hsb, wb, bq, bq, bq, (void*)Qb, nullptr, nullptr, SEQ, EMB, EMB, 0);
    k_f32_to_bf16<<<dim3(EE / 2048), cb, 0, stream>>>(wk, wb, (int)EE);
    k_qkv4<256, 256><<<dim3(128), dim3(512), 0, stream>>>(
        hsb, wb, bk, bk, bk, (void*)Kb, nullptr, nullptr, SEQ, EMB, EMB, 0);
    k_f32_to_bf16<<<dim3(EE / 2048), cb, 0, stream>>>(wv, wb, (int)EE);
    k_qkv4<256, 256><<<dim3(128), dim3(512), 0, stream>>>(
        hsb, wb, bv, bv, bv, (void*)VTb, nullptr, nullptr, SEQ, EMB, EMB, 2);
  }

  k_rope<<<dim3(SEQ * NH * HALF / 256), cb, 0, stream>>>(Qb, tab, qscale);
  k_rope<<<dim3(SEQ * NH * HALF / 256), cb, 0, stream>>>(Kb, tab, 1.0f);

  // attention: QB=128, grid 8x32 = 256 blocks (1 exact round), 4-buf pipeline
  k_flash<<<dim3(8, NH), dim3(512), 0, stream>>>(Qb, Kb, VTb, ctxb);

  // output projection: 128x256 tile -> grid 256 (1 exact round), f32 out
  k_f32_to_bf16<<<dim3(EE / 2048), cb, 0, stream>>>(wo, wb, (int)EE);
  k_qkv4<128, 256><<<dim3(256), dim3(512), 0, stream>>>(
      ctxb, wb, bo, bo, bo, d_out, nullptr, nullptr, SEQ, EMB, EMB, 1);
}

// Round 17
// 481.153 us; speedup vs baseline: 1.0714x; 1.0714x over previous
//
#include <hip/hip_runtime.h>
#include <hip/hip_bf16.h>

constexpr int SEQ = 2048;
constexpr int EMB = 4096;
constexpr int NH  = 32;
constexpr int HD  = 128;
constexpr int HALF = 64;

typedef __bf16 bf16x8 __attribute__((ext_vector_type(8)));
typedef float  f32x4  __attribute__((ext_vector_type(4)));
using u16 = unsigned short;
typedef u16 ushort8 __attribute__((ext_vector_type(8)));
typedef u16 u16x4 __attribute__((ext_vector_type(4)));

__device__ inline float bf2f(u16 u) {
  union { unsigned int i; float f; } v; v.i = ((unsigned int)u) << 16; return v.f;
}
__device__ inline u16 f2bf(float f) {
  union { __bf16 b; u16 u; } v; v.b = (__bf16)f; return v.u;
}

#define GLL16(gp, lp) __builtin_amdgcn_global_load_lds( \
    (const __attribute__((address_space(1))) void*)(gp), \
    (__attribute__((address_space(3))) void*)(lp), 16, 0, 0)

// ---------------- fp32 -> bf16 conversion (vectorized) ----------------
__global__ void k_f32_to_bf16(const float* __restrict__ in, u16* __restrict__ out, int n) {
  int i = (blockIdx.x * blockDim.x + threadIdx.x) * 8;
  if (i >= n) return;
  f32x4 a = *(const f32x4*)(in + i);
  f32x4 b = *(const f32x4*)(in + i + 4);
  ushort8 o;
  o[0] = f2bf(a[0]); o[1] = f2bf(a[1]); o[2] = f2bf(a[2]); o[3] = f2bf(a[3]);
  o[4] = f2bf(b[0]); o[5] = f2bf(b[1]); o[6] = f2bf(b[2]); o[7] = f2bf(b[3]);
  *(ushort8*)(out + i) = o;
}

// 3 weight matrices (each EMB*EMB = 2^24 elems) -> contiguous bf16 buffer
__global__ void k_w3_to_bf16(const float* __restrict__ w0, const float* __restrict__ w1,
                             const float* __restrict__ w2, u16* __restrict__ out) {
  size_t i = ((size_t)blockIdx.x * blockDim.x + threadIdx.x) * 8;
  int seg = (int)(i >> 24);
  size_t off = i & ((1u << 24) - 1);
  const float* src = (seg == 0) ? w0 : (seg == 1) ? w1 : w2;
  f32x4 a = *(const f32x4*)(src + off);
  f32x4 b = *(const f32x4*)(src + off + 4);
  ushort8 o;
  o[0] = f2bf(a[0]); o[1] = f2bf(a[1]); o[2] = f2bf(a[2]); o[3] = f2bf(a[3]);
  o[4] = f2bf(b[0]); o[5] = f2bf(b[1]); o[6] = f2bf(b[2]); o[7] = f2bf(b[3]);
  *(ushort8*)(out + i) = o;
}

// ---------------- RoPE cos/sin table (fp64 for exactness) ----------------
__global__ void k_rope_table(const int* __restrict__ pos, float* __restrict__ tab) {
  int idx = blockIdx.x * blockDim.x + threadIdx.x;
  if (idx >= SEQ * HALF) return;
  int s = idx >> 6, d = idx & 63;
  double invf = pow(10000.0, -(double)d / 64.0);
  double ang = (double)pos[s] * invf;
  tab[idx * 2]     = (float)cos(ang);
  tab[idx * 2 + 1] = (float)sin(ang);
}

// ---------------- RoPE apply to BOTH Q (with 1/sqrt(D) fold) and K, one launch ------
__global__ void k_rope2(u16* __restrict__ Qp, u16* __restrict__ Kp,
                        const float* __restrict__ tab, float qscale) {
  int idx = blockIdx.x * blockDim.x + threadIdx.x;   // 2*SEQ*NH*HALF
  int half = SEQ * NH * HALF;
  u16* X = (idx < half) ? Qp : Kp;
  float scale = (idx < half) ? qscale : 1.0f;
  int i = (idx < half) ? idx : idx - half;
  int d = i & 63;
  int h = (i >> 6) & 31;
  int s = i >> 11;
  u16* p = X + (size_t)s * EMB + h * HD + d;
  float x1 = bf2f(p[0]), x2 = bf2f(p[HALF]);
  float c  = tab[(s * HALF + d) * 2];
  float sn = tab[(s * HALF + d) * 2 + 1];
  p[0]    = f2bf((x1 * c - x2 * sn) * scale);
  p[HALF] = f2bf((x2 * c + x1 * sn) * scale);
}

// ======== GEMM (r14 structure, best measured): TBMxTBN, BK=32, 4 buffers, 3-ahead ====
// QKV 252 us @ TBN=192 (2 exact rounds). Counted vmcnt (2*LPT / LPT / 0), one raw
// barrier per tile, stage(t+3) after it into buf[(t-1)&3] (reads retired 1 tile ago).
// mode: 0 bf16 [M][N], 1 f32 [M][N], 2 bf16 V^T [n][M], 3 QKV fused.
template<int TBM, int TBN>
__global__ __launch_bounds__(512, 1) void k_qkv4(
    const u16* __restrict__ Ag, const u16* __restrict__ Wg,
    const float* __restrict__ b0, const float* __restrict__ b1, const float* __restrict__ b2,
    void* __restrict__ C0, void* __restrict__ C1, void* __restrict__ C2,
    int M, int N, int K, int mode)
{
  constexpr int LDA = TBM / 128;            // stageA loads per thread (2 or 1)
  constexpr int MA  = TBM / 32;             // A frags per wave (8 or 4)
  constexpr int NB  = TBN / 64;             // B frags per wave (4 or 3)
  constexpr int WNC = TBN / 4;              // cols per wave (64 or 48)
  __shared__ alignas(16) u16 As[4][TBM * 32];
  __shared__ alignas(16) u16 Bs[4][TBN * 32];

  int tid = threadIdx.x;
  int lane = tid & 63, wid = tid >> 6;
  int wm = wid >> 2, wn = wid & 3;          // 2 x 4 waves
  int l15 = lane & 15, lhi = lane >> 4;

  int NBY = M / TBM, NBX = N / TBN;
  int wg = blockIdx.x;
  int xcd = wg & 7, sgl = wg >> 3;
  int by = sgl % NBY, bxl = sgl / NBY;
  int bx = xcd * (NBX >> 3) + bxl;
  int m0 = by * TBM, n0 = bx * TBN;

  auto stageA = [&](int b, int k0) {
#pragma unroll
    for (int ld = 0; ld < LDA; ld++) {
      int idx = ld * 512 + tid;
      int row = idx >> 2, pb = idx & 3;
      int kb = (pb - row - (row >> 2)) & 3;
      GLL16(Ag + (size_t)(m0 + row) * K + k0 + kb * 8, &As[b][idx * 8]);
    }
  };
  auto stageB = [&](int b, int k0) {
    {
      int idx = tid;
      int row = idx >> 2, pb = idx & 3;
      int kb = (pb - row - (row >> 2)) & 3;
      GLL16(Wg + (size_t)(n0 + row) * K + k0 + kb * 8, &Bs[b][idx * 8]);
    }
    if constexpr (TBN == 256) {
      int idx = 512 + tid;
      int row = idx >> 2, pb = idx & 3;
      int kb = (pb - row - (row >> 2)) & 3;
      GLL16(Wg + (size_t)(n0 + row) * K + k0 + kb * 8, &Bs[b][idx * 8]);
    } else {
      if (wid < 4) {
        int idx = 512 + tid;
        int row = idx >> 2, pb = idx & 3;
        int kb = (pb - row - (row >> 2)) & 3;
        GLL16(Wg + (size_t)(n0 + row) * K + k0 + kb * 8, &Bs[b][idx * 8]);
      }
    }
  };

  f32x4 acc[MA][NB] = {};
  int KT = K >> 5;

  stageA(0, 0);  stageB(0, 0);
  stageA(1, 32); stageB(1, 32);
  stageA(2, 64); stageB(2, 64);

  for (int t = 0; t < KT; t++) {
    if constexpr (TBN == 256) {
      if (t < KT - 2)       asm volatile("s_waitcnt vmcnt(%0)" :: "n"(2 * (LDA + 2)) : "memory");
      else if (t == KT - 2) asm volatile("s_waitcnt vmcnt(%0)" :: "n"(LDA + 2) : "memory");
      else                  asm volatile("s_waitcnt vmcnt(0)" ::: "memory");
    } else {
      if (t < KT - 2) {
        if (wid < 4) asm volatile("s_waitcnt vmcnt(%0)" :: "n"(2 * (LDA + 2)) : "memory");
        else         asm volatile("s_waitcnt vmcnt(%0)" :: "n"(2 * (LDA + 1)) : "memory");
      } else if (t == KT - 2) {
        if (wid < 4) asm volatile("s_waitcnt vmcnt(%0)" :: "n"(LDA + 2) : "memory");
        else         asm volatile("s_waitcnt vmcnt(%0)" :: "n"(LDA + 1) : "memory");
      } else {
        asm volatile("s_waitcnt vmcnt(0)" ::: "memory");
      }
    }
    __builtin_amdgcn_s_barrier();
    __builtin_amdgcn_sched_barrier(0);

    const u16* as = &As[t & 3][0];
    const u16* bs = &Bs[t & 3][0];
    bool st = (t + 3) < KT;
    int sb = (t + 3) & 3, sk = (t + 3) << 5;

    bf16x8 bfr[NB], afA[MA / 2];
#pragma unroll
    for (int q = 0; q < NB; q++) {
      int row = wn * WNC + q * 16 + l15;
      bfr[q] = *(const bf16x8*)&bs[row * 32 + ((lhi + row + (row >> 2)) & 3) * 8];
    }
#pragma unroll
    for (int p = 0; p < MA / 2; p++) {
      int row = wm * (TBM / 2) + p * 16 + l15;
      afA[p] = *(const bf16x8*)&as[row * 32 + ((lhi + row + (row >> 2)) & 3) * 8];
    }
    if (st) stageA(sb, sk);
    __builtin_amdgcn_s_setprio(1);
#pragma unroll
    for (int p = 0; p < MA / 2; p++)
#pragma unroll
      for (int q = 0; q < NB; q++)
        acc[p][q] = __builtin_amdgcn_mfma_f32_16x16x32_bf16(afA[p], bfr[q], acc[p][q], 0, 0, 0);
    __builtin_amdgcn_s_setprio(0);

    bf16x8 afB[MA / 2];
#pragma unroll
    for (int p = 0; p < MA / 2; p++) {
      int row = wm * (TBM / 2) + (MA / 2) * 16 + p * 16 + l15;
      afB[p] = *(const bf16x8*)&as[row * 32 + ((lhi + row + (row >> 2)) & 3) * 8];
    }
    if (st) stageB(sb, sk);
    __builtin_amdgcn_s_setprio(1);
#pragma unroll
    for (int p = 0; p < MA / 2; p++)
#pragma unroll
      for (int q = 0; q < NB; q++)
        acc[MA / 2 + p][q] = __builtin_amdgcn_mfma_f32_16x16x32_bf16(afB[p], bfr[q], acc[MA / 2 + p][q], 0, 0, 0);
    __builtin_amdgcn_s_setprio(0);
  }

#pragma unroll
  for (int p = 0; p < MA; p++) {
    int m = m0 + wm * (TBM / 2) + p * 16 + lhi * 4;
#pragma unroll
    for (int q = 0; q < NB; q++) {
      int n = n0 + wn * WNC + q * 16 + l15;
      const float* bias; void* Cout; int mode_l, nl;
      if (mode == 3) {
        int seg = n >> 12; nl = n & 4095;
        bias = (seg == 0) ? b0 : (seg == 1) ? b1 : b2;
        Cout = (seg == 0) ? C0 : (seg == 1) ? C1 : C2;
        mode_l = (seg == 2) ? 2 : 0;
      } else { bias = b0; Cout = C0; mode_l = mode; nl = n; }
      float bs2 = bias[nl];
      if (mode_l == 2) {
        u16x4 pk;
#pragma unroll
        for (int r = 0; r < 4; r++) pk[r] = f2bf(acc[p][q][r] + bs2);
        *(u16x4*)&((u16*)Cout)[(size_t)nl * M + m] = pk;   // V^T
      } else if (mode_l == 1) {
#pragma unroll
        for (int r = 0; r < 4; r++)
          ((float*)Cout)[(size_t)(m + r) * EMB + nl] = acc[p][q][r] + bs2;
      } else {
#pragma unroll
        for (int r = 0; r < 4; r++)
          ((u16*)Cout)[(size_t)(m + r) * EMB + nl] = f2bf(acc[p][q][r] + bs2);
      }
    }
  }
}

// ---------------- Flash attention (causal), QB=128, KVB=64, 4-buf pipeline ----------------
constexpr int QB = 128, KVB = 64;

__global__ __launch_bounds__(512) void k_flash(
    const u16* __restrict__ Q, const u16* __restrict__ K, const u16* __restrict__ VT,
    u16* __restrict__ ctx)
{
  __shared__ alignas(16) u16 Ks[4][KVB * 128];   // 4 x 16 KB
  __shared__ alignas(16) u16 Vt[4][HD * 64];     // 4 x 16 KB
  __shared__ alignas(16) u16 Pl[8][16 * 64];     // 16 KB (144 KB total)

  int tid = threadIdx.x, lane = tid & 63, wid = tid >> 6;   // wid 0..7
  int l15 = lane & 15, lhi = lane >> 4;
  int h = blockIdx.y;

  auto stage = [&](int buf, int t2) {
    int kv = t2 * KVB;
#pragma unroll
    for (int it = 0; it < 2; it++) {
      int chunk = tid + it * 512;
      int r = chunk >> 4, bp = chunk & 15;
      GLL16(K + (size_t)(kv + r) * EMB + h * HD + (((bp - r) & 15) << 3), &Ks[buf][chunk * 8]);
    }
#pragma unroll
    for (int it = 0; it < 2; it++) {
      int chunk = tid + it * 512;
      int d = chunk >> 3, bp = chunk & 7;
      GLL16(VT + (size_t)(h * HD + d) * SEQ + kv + (((bp - d) & 7) << 3), &Vt[buf][chunk * 8]);
    }
  };

  for (int pi = 0; pi < 2; pi++) {
    int qb = pi ? (int)blockIdx.x : 15 - (int)blockIdx.x;   // heavy first
    int q0 = qb * QB;
    int qw = q0 + wid * 16;

    bf16x8 qf[4];
#pragma unroll
    for (int kc = 0; kc < 4; kc++)
      qf[kc] = *(const bf16x8*)&Q[(size_t)(qw + l15) * EMB + h * HD + kc * 32 + lhi * 8];

    f32x4 O[8] = {};
    float mrow[4], lrow[4];
#pragma unroll
    for (int r = 0; r < 4; r++) { mrow[r] = -3.0e38f; lrow[r] = 0.f; }

    int nt = 2 * (qb + 1);
    __syncthreads();          // pass boundary: previous pass's LDS reads done
    stage(0, 0);
    if (nt > 1) stage(1, 1);
    if (nt > 2) stage(2, 2);
    for (int t = 0; t < nt; t++) {
      if (t + 2 < nt)       asm volatile("s_waitcnt vmcnt(8)" ::: "memory");
      else if (t + 1 < nt)  asm volatile("s_waitcnt vmcnt(4)" ::: "memory");
      else                  asm volatile("s_waitcnt vmcnt(0)" ::: "memory");
      __builtin_amdgcn_s_barrier();
      __builtin_amdgcn_sched_barrier(0);
      if (t + 3 < nt) stage((t + 3) & 3, t + 3);

      int kv0 = t * KVB;
      if (kv0 > qw + 15) continue;   // fully masked for this wave (sync already uniform)

      const u16* ks = Ks[t & 3];
      const u16* vt = Vt[t & 3];
      float p[4][4];
      bool need_mask = (kv0 + KVB - 1) > qw;
#pragma unroll
      for (int c = 0; c < 4; c++) {
        f32x4 s = {};
        int r0 = c * 16 + l15;
#pragma unroll
        for (int kc = 0; kc < 4; kc++) {
          bf16x8 kf = *(const bf16x8*)&ks[r0 * 128 + (((kc * 4 + lhi) + r0) & 15) * 8];
          s = __builtin_amdgcn_mfma_f32_16x16x32_bf16(qf[kc], kf, s, 0, 0, 0);
        }
#pragma unroll
        for (int r = 0; r < 4; r++) {
          float sv = s[r];
          if (need_mask) {
            int qg = qw + lhi * 4 + r;
            int kg = kv0 + c * 16 + l15;
            if (kg > qg) sv = -3.0e38f;
          }
          p[c][r] = sv;
        }
      }
      float fscale[4];
#pragma unroll
      for (int r = 0; r < 4; r++) {
        float m = fmaxf(fmaxf(p[0][r], p[1][r]), fmaxf(p[2][r], p[3][r]));
#pragma unroll
        for (int x = 1; x < 16; x <<= 1) m = fmaxf(m, __shfl_xor(m, x, 64));
        float mnew = fmaxf(mrow[r], m);
        fscale[r] = __expf(mrow[r] - mnew);
        mrow[r] = mnew;
      }
#pragma unroll
      for (int c = 0; c < 4; c++)
#pragma unroll
        for (int r = 0; r < 4; r++)
          p[c][r] = __expf(p[c][r] - mrow[r]);
#pragma unroll
      for (int r = 0; r < 4; r++) {
        float s = p[0][r] + p[1][r] + p[2][r] + p[3][r];
#pragma unroll
        for (int x = 1; x < 16; x <<= 1) s += __shfl_xor(s, x, 64);
        lrow[r] = lrow[r] * fscale[r] + s;
      }
#pragma unroll
      for (int d = 0; d < 8; d++)
#pragma unroll
        for (int r = 0; r < 4; r++)
          O[d][r] *= fscale[r];
#pragma unroll
      for (int c = 0; c < 4; c++) {
        int kb = c * 2 + (l15 >> 3), klo = l15 & 7;
#pragma unroll
        for (int r = 0; r < 4; r++) {
          int q = lhi * 4 + r;
          Pl[wid][q * 64 + ((kb + (q >> 1)) & 7) * 8 + klo] = f2bf(p[c][r]);
        }
      }
#pragma unroll
      for (int ks2 = 0; ks2 < 2; ks2++) {
        int kb = ks2 * 4 + lhi;
        bf16x8 pf = *(const bf16x8*)&Pl[wid][l15 * 64 + ((kb + (l15 >> 1)) & 7) * 8];
#pragma unroll
        for (int ds = 0; ds < 8; ds++) {
          int d = ds * 16 + l15;
          bf16x8 vf = *(const bf16x8*)&vt[d * 64 + ((kb + d) & 7) * 8];
          O[ds] = __builtin_amdgcn_mfma_f32_16x16x32_bf16(pf, vf, O[ds], 0, 0, 0);
        }
      }
    }

#pragma unroll
    for (int r = 0; r < 4; r++) {
      float inv = 1.f / lrow[r];
      int qg = q0 + wid * 16 + lhi * 4 + r;
#pragma unroll
      for (int ds = 0; ds < 8; ds++)
        ctx[(size_t)qg * EMB + h * HD + ds * 16 + l15] = f2bf(O[ds][r] * inv);
    }
  }
}

// ---------------- launch ----------------
extern "C" void kernel_launch(void* const* d_in, const int* in_sizes, int n_in,
                              void* d_out, int out_size, void* d_ws, size_t ws_size,
                              hipStream_t stream) {
  const float* hs = (const float*)d_in[0];
  const float* wq = (const float*)d_in[1];
  const float* bq = (const float*)d_in[2];
  const float* wk = (const float*)d_in[3];
  const float* bk = (const float*)d_in[4];
  const float* wv = (const float*)d_in[5];
  const float* bv = (const float*)d_in[6];
  const float* wo = (const float*)d_in[7];
  const float* bo = (const float*)d_in[8];
  const int*  pos = (const int*)d_in[9];

  const size_t SE = (size_t)SEQ * EMB;   // 8M elems
  const size_t EE = (size_t)EMB * EMB;   // 16M elems = 2^24
  const float qscale = 1.0f / 11.313708498984761f;  // 1/sqrt(128)

  char* ws = (char*)d_ws;
  size_t off = 0;
  auto alloc = [&](size_t b) { size_t o = off; off += (b + 255) & ~(size_t)255; return o; };

  size_t need_fused = ((SE * 2 + 255) & ~255ULL) + ((EE * 6 + 255) & ~255ULL) +
                      3 * ((SE * 2 + 255) & ~255ULL) + ((size_t)SEQ * HALF * 8 + 255);
  bool fused = ws_size >= need_fused + 4096;

  u16*  hsb = (u16*)(ws + alloc(SE * 2));
  u16*  wb  = (u16*)(ws + alloc(fused ? EE * 6 : EE * 2));  // fused: wq|wk|wv, reused for wo
  u16*  Qb  = (u16*)(ws + alloc(SE * 2));
  u16*  Kb  = (u16*)(ws + alloc(SE * 2));
  u16*  VTb = (u16*)(ws + alloc(SE * 2));                   // V^T, [E][S]
  float* tab = (float*)(ws + alloc((size_t)SEQ * HALF * 2 * 4));
  u16*  ctxb = hsb;   // hs dead after QKV GEMM; flash output reuses it

  dim3 cb(256);
  k_f32_to_bf16<<<dim3(SE / 2048), cb, 0, stream>>>(hs, hsb, (int)SE);
  k_rope_table<<<dim3(SEQ * HALF / 256), cb, 0, stream>>>(pos, tab);

  if (fused) {
    k_w3_to_bf16<<<dim3(3 * EE / 2048), cb, 0, stream>>>(wq, wk, wv, wb);
    // fused QKV GEMM: 256x192 tile -> grid 512 = 2 EXACT rounds of 256 CUs
    k_qkv4<256, 192><<<dim3(512), dim3(512), 0, stream>>>(
        hsb, wb, bq, bk, bv, (void*)Qb, (void*)Kb, (void*)VTb, SEQ, 3 * EMB, EMB, 3);
  } else {
    k_f32_to_bf16<<<dim3(EE / 2048), cb, 0, stream>>>(wq, wb, (int)EE);
    k_qkv4<256, 256><<<dim3(128), dim3(512), 0, stream>>>(
        hsb, wb, bq, bq, bq, (void*)Qb, nullptr, nullptr, SEQ, EMB, EMB, 0);
    k_f32_to_bf16<<<dim3(EE / 2048), cb, 0, stream>>>(wk, wb, (int)EE);
    k_qkv4<256, 256><<<dim3(128), dim3(512), 0, stream>>>(
        hsb, wb, bk, bk, bk, (void*)Kb, nullptr, nullptr, SEQ, EMB, EMB, 0);
    k_f32_to_bf16<<<dim3(EE / 2048), cb, 0, stream>>>(wv, wb, (int)EE);
    k_qkv4<256, 256><<<dim3(128), dim3(512), 0, stream>>>(
        hsb, wb, bv, bv, bv, (void*)VTb, nullptr, nullptr, SEQ, EMB, EMB, 2);
  }

  // RoPE on Q (scaled) and K in ONE launch
  k_rope2<<<dim3(2 * SEQ * NH * HALF / 256), cb, 0, stream>>>(Qb, Kb, tab, qscale);

  // attention: QB=128, grid 8x32 = 256 blocks (1 exact round), 4-buf pipeline
  k_flash<<<dim3(8, NH), dim3(512), 0, stream>>>(Qb, Kb, VTb, ctxb);

  // output projection: 128x256 tile -> grid 256 (1 exact round), f32 out
  k_f32_to_bf16<<<dim3(EE / 2048), cb, 0, stream>>>(wo, wb, (int)EE);
  k_qkv4<128, 256><<<dim3(256), dim3(512), 0, stream>>>(
      ctxb, wb, bo, bo, bo, d_out, nullptr, nullptr, SEQ, EMB, EMB, 1);
}

// Round 18
// 476.645 us; speedup vs baseline: 1.0815x; 1.0095x over previous
//
#include <hip/hip_runtime.h>
#include <hip/hip_bf16.h>

constexpr int SEQ = 2048;
constexpr int EMB = 4096;
constexpr int NH  = 32;
constexpr int HD  = 128;
constexpr int HALF = 64;

typedef __bf16 bf16x8 __attribute__((ext_vector_type(8)));
typedef float  f32x4  __attribute__((ext_vector_type(4)));
using u16 = unsigned short;
typedef u16 ushort8 __attribute__((ext_vector_type(8)));
typedef u16 u16x4 __attribute__((ext_vector_type(4)));

__device__ inline float bf2f(u16 u) {
  union { unsigned int i; float f; } v; v.i = ((unsigned int)u) << 16; return v.f;
}
__device__ inline u16 f2bf(float f) {
  union { __bf16 b; u16 u; } v; v.b = (__bf16)f; return v.u;
}

#define GLL16(gp, lp) __builtin_amdgcn_global_load_lds( \
    (const __attribute__((address_space(1))) void*)(gp), \
    (__attribute__((address_space(3))) void*)(lp), 16, 0, 0)

// ---------------- fp32 -> bf16 conversion (vectorized) ----------------
__global__ void k_f32_to_bf16(const float* __restrict__ in, u16* __restrict__ out, int n) {
  int i = (blockIdx.x * blockDim.x + threadIdx.x) * 8;
  if (i >= n) return;
  f32x4 a = *(const f32x4*)(in + i);
  f32x4 b = *(const f32x4*)(in + i + 4);
  ushort8 o;
  o[0] = f2bf(a[0]); o[1] = f2bf(a[1]); o[2] = f2bf(a[2]); o[3] = f2bf(a[3]);
  o[4] = f2bf(b[0]); o[5] = f2bf(b[1]); o[6] = f2bf(b[2]); o[7] = f2bf(b[3]);
  *(ushort8*)(out + i) = o;
}

// 3 weight matrices (each EMB*EMB = 2^24 elems) -> contiguous bf16 buffer
__global__ void k_w3_to_bf16(const float* __restrict__ w0, const float* __restrict__ w1,
                             const float* __restrict__ w2, u16* __restrict__ out) {
  size_t i = ((size_t)blockIdx.x * blockDim.x + threadIdx.x) * 8;
  int seg = (int)(i >> 24);
  size_t off = i & ((1u << 24) - 1);
  const float* src = (seg == 0) ? w0 : (seg == 1) ? w1 : w2;
  f32x4 a = *(const f32x4*)(src + off);
  f32x4 b = *(const f32x4*)(src + off + 4);
  ushort8 o;
  o[0] = f2bf(a[0]); o[1] = f2bf(a[1]); o[2] = f2bf(a[2]); o[3] = f2bf(a[3]);
  o[4] = f2bf(b[0]); o[5] = f2bf(b[1]); o[6] = f2bf(b[2]); o[7] = f2bf(b[3]);
  *(ushort8*)(out + i) = o;
}

// ---------------- RoPE cos/sin table (fp64 for exactness) ----------------
__global__ void k_rope_table(const int* __restrict__ pos, float* __restrict__ tab) {
  int idx = blockIdx.x * blockDim.x + threadIdx.x;
  if (idx >= SEQ * HALF) return;
  int s = idx >> 6, d = idx & 63;
  double invf = pow(10000.0, -(double)d / 64.0);
  double ang = (double)pos[s] * invf;
  tab[idx * 2]     = (float)cos(ang);
  tab[idx * 2 + 1] = (float)sin(ang);
}

// ------- RoPE, vectorized (ushort8 = 16B/lane): Q (scaled) and K in one launch -------
// Thread i handles one 8-wide d-block of one (s,h): loads x1[d..d+7] and
// x2[d+64..d+71] as ushort8 (both rotation-pair halves are contiguous runs),
// 16 contiguous table floats, stores 2x ushort8.
__global__ void k_rope2v(u16* __restrict__ Qp, u16* __restrict__ Kp,
                         const float* __restrict__ tab, float qscale) {
  int idx = blockIdx.x * blockDim.x + threadIdx.x;   // 2*SEQ*NH*8
  int half = SEQ * NH * 8;
  u16* X = (idx < half) ? Qp : Kp;
  float scale = (idx < half) ? qscale : 1.0f;
  int i = (idx < half) ? idx : idx - half;
  int db = i & 7;          // d-block (8 elems)
  int h  = (i >> 3) & 31;
  int s  = i >> 8;
  u16* p = X + (size_t)s * EMB + h * HD + db * 8;
  ushort8 a = *(ushort8*)p;            // x1: d = db*8 .. +7
  ushort8 b = *(ushort8*)(p + HALF);   // x2: d+64
  const float* tb = tab + ((size_t)s * HALF + db * 8) * 2;   // 16 floats (c,s pairs)
  ushort8 o1, o2;
#pragma unroll
  for (int j = 0; j < 8; j++) {
    float c  = tb[2 * j];
    float sn = tb[2 * j + 1];
    float x1 = bf2f(a[j]), x2 = bf2f(b[j]);
    o1[j] = f2bf((x1 * c - x2 * sn) * scale);
    o2[j] = f2bf((x2 * c + x1 * sn) * scale);
  }
  *(ushort8*)p          = o1;
  *(ushort8*)(p + HALF) = o2;
}

// ======== GEMM (r14 structure, best measured): TBMxTBN, BK=32, 4 buffers, 3-ahead ====
// QKV 252 us @ TBN=192 (2 exact rounds). Counted vmcnt (2*LPT / LPT / 0), one raw
// barrier per tile, stage(t+3) after it into buf[(t-1)&3] (reads retired 1 tile ago).
// mode: 0 bf16 [M][N], 1 f32 [M][N], 2 bf16 V^T [n][M], 3 QKV fused.
template<int TBM, int TBN>
__global__ __launch_bounds__(512, 1) void k_qkv4(
    const u16* __restrict__ Ag, const u16* __restrict__ Wg,
    const float* __restrict__ b0, const float* __restrict__ b1, const float* __restrict__ b2,
    void* __restrict__ C0, void* __restrict__ C1, void* __restrict__ C2,
    int M, int N, int K, int mode)
{
  constexpr int LDA = TBM / 128;            // stageA loads per thread (2 or 1)
  constexpr int MA  = TBM / 32;             // A frags per wave (8 or 4)
  constexpr int NB  = TBN / 64;             // B frags per wave (4 or 3)
  constexpr int WNC = TBN / 4;              // cols per wave (64 or 48)
  __shared__ alignas(16) u16 As[4][TBM * 32];
  __shared__ alignas(16) u16 Bs[4][TBN * 32];

  int tid = threadIdx.x;
  int lane = tid & 63, wid = tid >> 6;
  int wm = wid >> 2, wn = wid & 3;          // 2 x 4 waves
  int l15 = lane & 15, lhi = lane >> 4;

  int NBY = M / TBM, NBX = N / TBN;
  int wg = blockIdx.x;
  int xcd = wg & 7, sgl = wg >> 3;
  int by = sgl % NBY, bxl = sgl / NBY;
  int bx = xcd * (NBX >> 3) + bxl;
  int m0 = by * TBM, n0 = bx * TBN;

  auto stageA = [&](int b, int k0) {
#pragma unroll
    for (int ld = 0; ld < LDA; ld++) {
      int idx = ld * 512 + tid;
      int row = idx >> 2, pb = idx & 3;
      int kb = (pb - row - (row >> 2)) & 3;
      GLL16(Ag + (size_t)(m0 + row) * K + k0 + kb * 8, &As[b][idx * 8]);
    }
  };
  auto stageB = [&](int b, int k0) {
    {
      int idx = tid;
      int row = idx >> 2, pb = idx & 3;
      int kb = (pb - row - (row >> 2)) & 3;
      GLL16(Wg + (size_t)(n0 + row) * K + k0 + kb * 8, &Bs[b][idx * 8]);
    }
    if constexpr (TBN == 256) {
      int idx = 512 + tid;
      int row = idx >> 2, pb = idx & 3;
      int kb = (pb - row - (row >> 2)) & 3;
      GLL16(Wg + (size_t)(n0 + row) * K + k0 + kb * 8, &Bs[b][idx * 8]);
    } else {
      if (wid < 4) {
        int idx = 512 + tid;
        int row = idx >> 2, pb = idx & 3;
        int kb = (pb - row - (row >> 2)) & 3;
        GLL16(Wg + (size_t)(n0 + row) * K + k0 + kb * 8, &Bs[b][idx * 8]);
      }
    }
  };

  f32x4 acc[MA][NB] = {};
  int KT = K >> 5;

  stageA(0, 0);  stageB(0, 0);
  stageA(1, 32); stageB(1, 32);
  stageA(2, 64); stageB(2, 64);

  for (int t = 0; t < KT; t++) {
    if constexpr (TBN == 256) {
      if (t < KT - 2)       asm volatile("s_waitcnt vmcnt(%0)" :: "n"(2 * (LDA + 2)) : "memory");
      else if (t == KT - 2) asm volatile("s_waitcnt vmcnt(%0)" :: "n"(LDA + 2) : "memory");
      else                  asm volatile("s_waitcnt vmcnt(0)" ::: "memory");
    } else {
      if (t < KT - 2) {
        if (wid < 4) asm volatile("s_waitcnt vmcnt(%0)" :: "n"(2 * (LDA + 2)) : "memory");
        else         asm volatile("s_waitcnt vmcnt(%0)" :: "n"(2 * (LDA + 1)) : "memory");
      } else if (t == KT - 2) {
        if (wid < 4) asm volatile("s_waitcnt vmcnt(%0)" :: "n"(LDA + 2) : "memory");
        else         asm volatile("s_waitcnt vmcnt(%0)" :: "n"(LDA + 1) : "memory");
      } else {
        asm volatile("s_waitcnt vmcnt(0)" ::: "memory");
      }
    }
    __builtin_amdgcn_s_barrier();
    __builtin_amdgcn_sched_barrier(0);

    const u16* as = &As[t & 3][0];
    const u16* bs = &Bs[t & 3][0];
    bool st = (t + 3) < KT;
    int sb = (t + 3) & 3, sk = (t + 3) << 5;

    bf16x8 bfr[NB], afA[MA / 2];
#pragma unroll
    for (int q = 0; q < NB; q++) {
      int row = wn * WNC + q * 16 + l15;
      bfr[q] = *(const bf16x8*)&bs[row * 32 + ((lhi + row + (row >> 2)) & 3) * 8];
    }
#pragma unroll
    for (int p = 0; p < MA / 2; p++) {
      int row = wm * (TBM / 2) + p * 16 + l15;
      afA[p] = *(const bf16x8*)&as[row * 32 + ((lhi + row + (row >> 2)) & 3) * 8];
    }
    if (st) stageA(sb, sk);
    __builtin_amdgcn_s_setprio(1);
#pragma unroll
    for (int p = 0; p < MA / 2; p++)
#pragma unroll
      for (int q = 0; q < NB; q++)
        acc[p][q] = __builtin_amdgcn_mfma_f32_16x16x32_bf16(afA[p], bfr[q], acc[p][q], 0, 0, 0);
    __builtin_amdgcn_s_setprio(0);

    bf16x8 afB[MA / 2];
#pragma unroll
    for (int p = 0; p < MA / 2; p++) {
      int row = wm * (TBM / 2) + (MA / 2) * 16 + p * 16 + l15;
      afB[p] = *(const bf16x8*)&as[row * 32 + ((lhi + row + (row >> 2)) & 3) * 8];
    }
    if (st) stageB(sb, sk);
    __builtin_amdgcn_s_setprio(1);
#pragma unroll
    for (int p = 0; p < MA / 2; p++)
#pragma unroll
      for (int q = 0; q < NB; q++)
        acc[MA / 2 + p][q] = __builtin_amdgcn_mfma_f32_16x16x32_bf16(afB[p], bfr[q], acc[MA / 2 + p][q], 0, 0, 0);
    __builtin_amdgcn_s_setprio(0);
  }

#pragma unroll
  for (int p = 0; p < MA; p++) {
    int m = m0 + wm * (TBM / 2) + p * 16 + lhi * 4;
#pragma unroll
    for (int q = 0; q < NB; q++) {
      int n = n0 + wn * WNC + q * 16 + l15;
      const float* bias; void* Cout; int mode_l, nl;
      if (mode == 3) {
        int seg = n >> 12; nl = n & 4095;
        bias = (seg == 0) ? b0 : (seg == 1) ? b1 : b2;
        Cout = (seg == 0) ? C0 : (seg == 1) ? C1 : C2;
        mode_l = (seg == 2) ? 2 : 0;
      } else { bias = b0; Cout = C0; mode_l = mode; nl = n; }
      float bs2 = bias[nl];
      if (mode_l == 2) {
        u16x4 pk;
#pragma unroll
        for (int r = 0; r < 4; r++) pk[r] = f2bf(acc[p][q][r] + bs2);
        *(u16x4*)&((u16*)Cout)[(size_t)nl * M + m] = pk;   // V^T
      } else if (mode_l == 1) {
#pragma unroll
        for (int r = 0; r < 4; r++)
          ((float*)Cout)[(size_t)(m + r) * EMB + nl] = acc[p][q][r] + bs2;
      } else {
#pragma unroll
        for (int r = 0; r < 4; r++)
          ((u16*)Cout)[(size_t)(m + r) * EMB + nl] = f2bf(acc[p][q][r] + bs2);
      }
    }
  }
}

// ---------------- Flash attention (causal), QB=128, KVB=64, 4-buf pipeline ----------------
constexpr int QB = 128, KVB = 64;

__global__ __launch_bounds__(512) void k_flash(
    const u16* __restrict__ Q, const u16* __restrict__ K, const u16* __restrict__ VT,
    u16* __restrict__ ctx)
{
  __shared__ alignas(16) u16 Ks[4][KVB * 128];   // 4 x 16 KB
  __shared__ alignas(16) u16 Vt[4][HD * 64];     // 4 x 16 KB
  __shared__ alignas(16) u16 Pl[8][16 * 64];     // 16 KB (144 KB total)

  int tid = threadIdx.x, lane = tid & 63, wid = tid >> 6;   // wid 0..7
  int l15 = lane & 15, lhi = lane >> 4;
  int h = blockIdx.y;

  auto stage = [&](int buf, int t2) {
    int kv = t2 * KVB;
#pragma unroll
    for (int it = 0; it < 2; it++) {
      int chunk = tid + it * 512;
      int r = chunk >> 4, bp = chunk & 15;
      GLL16(K + (size_t)(kv + r) * EMB + h * HD + (((bp - r) & 15) << 3), &Ks[buf][chunk * 8]);
    }
#pragma unroll
    for (int it = 0; it < 2; it++) {
      int chunk = tid + it * 512;
      int d = chunk >> 3, bp = chunk & 7;
      GLL16(VT + (size_t)(h * HD + d) * SEQ + kv + (((bp - d) & 7) << 3), &Vt[buf][chunk * 8]);
    }
  };

  for (int pi = 0; pi < 2; pi++) {
    int qb = pi ? (int)blockIdx.x : 15 - (int)blockIdx.x;   // heavy first
    int q0 = qb * QB;
    int qw = q0 + wid * 16;

    bf16x8 qf[4];
#pragma unroll
    for (int kc = 0; kc < 4; kc++)
      qf[kc] = *(const bf16x8*)&Q[(size_t)(qw + l15) * EMB + h * HD + kc * 32 + lhi * 8];

    f32x4 O[8] = {};
    float mrow[4], lrow[4];
#pragma unroll
    for (int r = 0; r < 4; r++) { mrow[r] = -3.0e38f; lrow[r] = 0.f; }

    int nt = 2 * (qb + 1);
    __syncthreads();          // pass boundary: previous pass's LDS reads done
    stage(0, 0);
    if (nt > 1) stage(1, 1);
    if (nt > 2) stage(2, 2);
    for (int t = 0; t < nt; t++) {
      if (t + 2 < nt)       asm volatile("s_waitcnt vmcnt(8)" ::: "memory");
      else if (t + 1 < nt)  asm volatile("s_waitcnt vmcnt(4)" ::: "memory");
      else                  asm volatile("s_waitcnt vmcnt(0)" ::: "memory");
      __builtin_amdgcn_s_barrier();
      __builtin_amdgcn_sched_barrier(0);
      if (t + 3 < nt) stage((t + 3) & 3, t + 3);

      int kv0 = t * KVB;
      if (kv0 > qw + 15) continue;   // fully masked for this wave (sync already uniform)

      const u16* ks = Ks[t & 3];
      const u16* vt = Vt[t & 3];
      float p[4][4];
      bool need_mask = (kv0 + KVB - 1) > qw;
#pragma unroll
      for (int c = 0; c < 4; c++) {
        f32x4 s = {};
        int r0 = c * 16 + l15;
#pragma unroll
        for (int kc = 0; kc < 4; kc++) {
          bf16x8 kf = *(const bf16x8*)&ks[r0 * 128 + (((kc * 4 + lhi) + r0) & 15) * 8];
          s = __builtin_amdgcn_mfma_f32_16x16x32_bf16(qf[kc], kf, s, 0, 0, 0);
        }
#pragma unroll
        for (int r = 0; r < 4; r++) {
          float sv = s[r];
          if (need_mask) {
            int qg = qw + lhi * 4 + r;
            int kg = kv0 + c * 16 + l15;
            if (kg > qg) sv = -3.0e38f;
          }
          p[c][r] = sv;
        }
      }
      float fscale[4];
#pragma unroll
      for (int r = 0; r < 4; r++) {
        float m = fmaxf(fmaxf(p[0][r], p[1][r]), fmaxf(p[2][r], p[3][r]));
#pragma unroll
        for (int x = 1; x < 16; x <<= 1) m = fmaxf(m, __shfl_xor(m, x, 64));
        float mnew = fmaxf(mrow[r], m);
        fscale[r] = __expf(mrow[r] - mnew);
        mrow[r] = mnew;
      }
#pragma unroll
      for (int c = 0; c < 4; c++)
#pragma unroll
        for (int r = 0; r < 4; r++)
          p[c][r] = __expf(p[c][r] - mrow[r]);
#pragma unroll
      for (int r = 0; r < 4; r++) {
        float s = p[0][r] + p[1][r] + p[2][r] + p[3][r];
#pragma unroll
        for (int x = 1; x < 16; x <<= 1) s += __shfl_xor(s, x, 64);
        lrow[r] = lrow[r] * fscale[r] + s;
      }
#pragma unroll
      for (int d = 0; d < 8; d++)
#pragma unroll
        for (int r = 0; r < 4; r++)
          O[d][r] *= fscale[r];
#pragma unroll
      for (int c = 0; c < 4; c++) {
        int kb = c * 2 + (l15 >> 3), klo = l15 & 7;
#pragma unroll
        for (int r = 0; r < 4; r++) {
          int q = lhi * 4 + r;
          Pl[wid][q * 64 + ((kb + (q >> 1)) & 7) * 8 + klo] = f2bf(p[c][r]);
        }
      }
#pragma unroll
      for (int ks2 = 0; ks2 < 2; ks2++) {
        int kb = ks2 * 4 + lhi;
        bf16x8 pf = *(const bf16x8*)&Pl[wid][l15 * 64 + ((kb + (l15 >> 1)) & 7) * 8];
#pragma unroll
        for (int ds = 0; ds < 8; ds++) {
          int d = ds * 16 + l15;
          bf16x8 vf = *(const bf16x8*)&vt[d * 64 + ((kb + d) & 7) * 8];
          O[ds] = __builtin_amdgcn_mfma_f32_16x16x32_bf16(pf, vf, O[ds], 0, 0, 0);
        }
      }
    }

#pragma unroll
    for (int r = 0; r < 4; r++) {
      float inv = 1.f / lrow[r];
      int qg = q0 + wid * 16 + lhi * 4 + r;
#pragma unroll
      for (int ds = 0; ds < 8; ds++)
        ctx[(size_t)qg * EMB + h * HD + ds * 16 + l15] = f2bf(O[ds][r] * inv);
    }
  }
}

// ---------------- launch ----------------
extern "C" void kernel_launch(void* const* d_in, const int* in_sizes, int n_in,
                              void* d_out, int out_size, void* d_ws, size_t ws_size,
                              hipStream_t stream) {
  const float* hs = (const float*)d_in[0];
  const float* wq = (const float*)d_in[1];
  const float* bq = (const float*)d_in[2];
  const float* wk = (const float*)d_in[3];
  const float* bk = (const float*)d_in[4];
  const float* wv = (const float*)d_in[5];
  const float* bv = (const float*)d_in[6];
  const float* wo = (const float*)d_in[7];
  const float* bo = (const float*)d_in[8];
  const int*  pos = (const int*)d_in[9];

  const size_t SE = (size_t)SEQ * EMB;   // 8M elems
  const size_t EE = (size_t)EMB * EMB;   // 16M elems = 2^24
  const float qscale = 1.0f / 11.313708498984761f;  // 1/sqrt(128)

  char* ws = (char*)d_ws;
  size_t off = 0;
  auto alloc = [&](size_t b) { size_t o = off; off += (b + 255) & ~(size_t)255; return o; };

  size_t need_fused = ((SE * 2 + 255) & ~255ULL) + ((EE * 6 + 255) & ~255ULL) +
                      3 * ((SE * 2 + 255) & ~255ULL) + ((size_t)SEQ * HALF * 8 + 255);
  bool fused = ws_size >= need_fused + 4096;

  u16*  hsb = (u16*)(ws + alloc(SE * 2));
  u16*  wb  = (u16*)(ws + alloc(fused ? EE * 6 : EE * 2));  // fused: wq|wk|wv, reused for wo
  u16*  Qb  = (u16*)(ws + alloc(SE * 2));
  u16*  Kb  = (u16*)(ws + alloc(SE * 2));
  u16*  VTb = (u16*)(ws + alloc(SE * 2));                   // V^T, [E][S]
  float* tab = (float*)(ws + alloc((size_t)SEQ * HALF * 2 * 4));
  u16*  ctxb = hsb;   // hs dead after QKV GEMM; flash output reuses it

  dim3 cb(256);
  k_f32_to_bf16<<<dim3(SE / 2048), cb, 0, stream>>>(hs, hsb, (int)SE);
  k_rope_table<<<dim3(SEQ * HALF / 256), cb, 0, stream>>>(pos, tab);

  if (fused) {
    k_w3_to_bf16<<<dim3(3 * EE / 2048), cb, 0, stream>>>(wq, wk, wv, wb);
    // fused QKV GEMM: 256x192 tile -> grid 512 = 2 EXACT rounds of 256 CUs
    k_qkv4<256, 192><<<dim3(512), dim3(512), 0, stream>>>(
        hsb, wb, bq, bk, bv, (void*)Qb, (void*)Kb, (void*)VTb, SEQ, 3 * EMB, EMB, 3);
  } else {
    k_f32_to_bf16<<<dim3(EE / 2048), cb, 0, stream>>>(wq, wb, (int)EE);
    k_qkv4<256, 256><<<dim3(128), dim3(512), 0, stream>>>(
        hsb, wb, bq, bq, bq, (void*)Qb, nullptr, nullptr, SEQ, EMB, EMB, 0);
    k_f32_to_bf16<<<dim3(EE / 2048), cb, 0, stream>>>(wk, wb, (int)EE);
    k_qkv4<256, 256><<<dim3(128), dim3(512), 0, stream>>>(
        hsb, wb, bk, bk, bk, (void*)Kb, nullptr, nullptr, SEQ, EMB, EMB, 0);
    k_f32_to_bf16<<<dim3(EE / 2048), cb, 0, stream>>>(wv, wb, (int)EE);
    k_qkv4<256, 256><<<dim3(128), dim3(512), 0, stream>>>(
        hsb, wb, bv, bv, bv, (void*)VTb, nullptr, nullptr, SEQ, EMB, EMB, 2);
  }

  // RoPE on Q (scaled) and K, vectorized (16B/lane), one launch
  k_rope2v<<<dim3(2 * SEQ * NH * 8 / 256), cb, 0, stream>>>(Qb, Kb, tab, qscale);

  // attention: QB=128, grid 8x32 = 256 blocks (1 exact round), 4-buf pipeline
  k_flash<<<dim3(8, NH), dim3(512), 0, stream>>>(Qb, Kb, VTb, ctxb);

  // output projection: 128x256 tile -> grid 256 (1 exact round), f32 out
  k_f32_to_bf16<<<dim3(EE / 2048), cb, 0, stream>>>(wo, wb, (int)EE);
  k_qkv4<128, 256><<<dim3(256), dim3(512), 0, stream>>>(
      ctxb, wb, bo, bo, bo, d_out, nullptr, nullptr, SEQ, EMB, EMB, 1);
}